// Round 1
// baseline (336.499 us; speedup 1.0000x reference)
//
#include <hip/hip_runtime.h>
#include <hip/hip_bf16.h>

#define L_LEN 131072
#define H_DIM 128
#define P_DIM 128
#define CHUNK 256
#define NCHUNK (L_LEN / CHUNK)   // 512
#define BT 16

// ---- workspace layout (float offsets) ----
constexpr size_t OFF_BU  = 0;
constexpr size_t N_BU    = (size_t)L_LEN * P_DIM * 2;          // 33,554,432 floats
constexpr size_t OFF_DA  = OFF_BU + N_BU;
constexpr size_t OFF_SC  = OFF_DA + 2 * P_DIM;
constexpr size_t OFF_POW = OFF_SC + 2 * P_DIM;
constexpr size_t N_POW   = (size_t)(CHUNK + 1) * P_DIM * 2;    // 65,792
constexpr size_t OFF_DBT = OFF_POW + N_POW;
constexpr size_t OFF_CT  = OFF_DBT + (size_t)P_DIM * H_DIM * 2;
constexpr size_t OFF_E   = OFF_CT + (size_t)P_DIM * H_DIM * 2;
constexpr size_t OFF_HIN = OFF_E + (size_t)NCHUNK * P_DIM * 2;
// total ≈ 135.8 MB of ws

__device__ __forceinline__ float2 cfma(float2 a, float2 h, float2 c) {
    // a*h + c (complex)
    float2 r;
    r.x = fmaf(a.x, h.x, fmaf(-a.y, h.y, c.x));
    r.y = fmaf(a.x, h.y, fmaf(a.y, h.x, c.y));
    return r;
}

// ---- k0a: per-mode scalars + dA power table (1 block, 128 threads) ----
__global__ void k0a(const float* __restrict__ Arl, const float* __restrict__ Ai,
                    const float* __restrict__ invdt,
                    float* __restrict__ dA, float* __restrict__ sc,
                    float* __restrict__ dApow) {
    int p = threadIdx.x;
    if (p >= P_DIM) return;
    float idt = invdt[p];
    float dt = (idt > 20.f) ? idt : log1pf(expf(idt));   // softplus
    float ar = Arl[p], ai = Ai[p];
    float zr = 0.5f * dt * ar, zi = 0.5f * dt * ai;
    // BL = 1/(1-z)
    float dr = 1.f - zr, di = -zi;
    float inv = 1.f / (dr * dr + di * di);
    float blr = dr * inv, bli = -di * inv;
    // dA = BL*(1+z)
    float nr = 1.f + zr, ni = zi;
    float dar = fmaf(blr, nr, -bli * ni);
    float dai = fmaf(blr, ni,  bli * nr);
    dA[2 * p] = dar; dA[2 * p + 1] = dai;
    sc[2 * p] = blr * dt; sc[2 * p + 1] = bli * dt;
    // dA^k table, k = 0..CHUNK
    float pr = 1.f, pi = 0.f;
    dApow[p * 2] = pr; dApow[p * 2 + 1] = pi;
    for (int k = 1; k <= CHUNK; ++k) {
        float npr = fmaf(pr, dar, -pi * dai);
        float npi = fmaf(pr, dai,  pi * dar);
        pr = npr; pi = npi;
        dApow[((size_t)k * P_DIM + p) * 2]     = pr;
        dApow[((size_t)k * P_DIM + p) * 2 + 1] = pi;
    }
}

// ---- k0b: build dB (transposed [h][p]) and C (transposed [p][h]) ----
__global__ void k0b(const float* __restrict__ Bre, const float* __restrict__ Bim,
                    const float* __restrict__ Cre, const float* __restrict__ Cim,
                    const float* __restrict__ sc,
                    float* __restrict__ dBt, float* __restrict__ Ct) {
    int i = blockIdx.x * 256 + threadIdx.x;      // 0..16383
    // dB[p][h] = sc[p] * (Bre + i Bim)[p][h]  -> store at dBt[h][p]
    int p = i >> 7, h = i & 127;
    float2 s = ((const float2*)sc)[p];
    float br = Bre[i], bi = Bim[i];
    float2 v;
    v.x = fmaf(s.x, br, -s.y * bi);
    v.y = fmaf(s.x, bi,  s.y * br);
    ((float2*)dBt)[h * P_DIM + p] = v;
    // C layout (H,P): element [h2][p2]; store at Ct[p2][h2]
    int h2 = i >> 7, p2 = i & 127;
    float2 c; c.x = Cre[i]; c.y = Cim[i];
    ((float2*)Ct)[p2 * H_DIM + h2] = c;
}

// ---- k1: Bu[l][p] = sum_h x[l][h] * dB[p][h]  (64 rows x 128 p per block) ----
#define K1_ROWS 64
__global__ __launch_bounds__(256, 2) void k1(const float* __restrict__ x,
                                             const float* __restrict__ dBt,
                                             float* __restrict__ Bu) {
    __shared__ float  xs[K1_ROWS][32];    // 8 KB
    __shared__ float2 dBs[32][128];       // 32 KB
    int t = threadIdx.x;
    int l0 = blockIdx.x * K1_ROWS;
    int tp = t & 31, tr = t >> 5;         // p-lane, row-group
    float2 acc[8][4];
    #pragma unroll
    for (int j = 0; j < 8; ++j)
        #pragma unroll
        for (int jj = 0; jj < 4; ++jj) acc[j][jj] = make_float2(0.f, 0.f);

    for (int ht = 0; ht < 4; ++ht) {
        int h0 = ht * 32;
        __syncthreads();
        // stage xs: 64x32 floats = 512 float4, 2 per thread
        #pragma unroll
        for (int j = 0; j < 2; ++j) {
            int f = j * 256 + t;
            int row = f >> 3, c4 = f & 7;
            float4 v = *(const float4*)(x + (size_t)(l0 + row) * H_DIM + h0 + c4 * 4);
            *(float4*)(&xs[row][c4 * 4]) = v;
        }
        // stage dBs: 32h x 128p complex = 2048 float4, 8 per thread (dBt is [h][p])
        #pragma unroll
        for (int j = 0; j < 8; ++j) {
            int f = j * 256 + t;
            int hh = f >> 6, p4 = f & 63;
            float4 v = *(const float4*)(dBt + ((size_t)(h0 + hh) * P_DIM + p4 * 2) * 2);
            *(float4*)(&dBs[hh][p4 * 2]) = v;
        }
        __syncthreads();
        for (int hh = 0; hh < 32; ++hh) {
            float xv[8]; float2 dbv[4];
            #pragma unroll
            for (int j = 0; j < 8; ++j) xv[j] = xs[tr * 8 + j][hh];
            #pragma unroll
            for (int jj = 0; jj < 4; ++jj) dbv[jj] = dBs[hh][tp + 32 * jj];
            #pragma unroll
            for (int j = 0; j < 8; ++j)
                #pragma unroll
                for (int jj = 0; jj < 4; ++jj) {
                    acc[j][jj].x = fmaf(xv[j], dbv[jj].x, acc[j][jj].x);
                    acc[j][jj].y = fmaf(xv[j], dbv[jj].y, acc[j][jj].y);
                }
        }
    }
    float2* bu = (float2*)Bu;
    #pragma unroll
    for (int j = 0; j < 8; ++j)
        #pragma unroll
        for (int jj = 0; jj < 4; ++jj)
            bu[(size_t)(l0 + tr * 8 + j) * P_DIM + tp + 32 * jj] = acc[j][jj];
}

// ---- k2: per-chunk local scans; overwrite Bu with h_local; emit end states ----
__global__ __launch_bounds__(256) void k2(float* __restrict__ Bu,
                                          const float* __restrict__ dA,
                                          float* __restrict__ E) {
    int t = threadIdx.x;
    int p = t & 127;
    int g = blockIdx.x * 2 + (t >> 7);
    float2 a = ((const float2*)dA)[p];
    float2* bu = (float2*)Bu + (size_t)g * CHUNK * P_DIM + p;
    float2 h = make_float2(0.f, 0.f);
    float2 buf[BT], nbuf[BT];
    #pragma unroll
    for (int i = 0; i < BT; ++i) buf[i] = bu[i * P_DIM];
    const int NB = CHUNK / BT;
    for (int b = 0; b < NB; ++b) {
        if (b + 1 < NB) {
            #pragma unroll
            for (int i = 0; i < BT; ++i) nbuf[i] = bu[((b + 1) * BT + i) * P_DIM];
        }
        #pragma unroll
        for (int i = 0; i < BT; ++i) {
            h = cfma(a, h, buf[i]);
            bu[(b * BT + i) * P_DIM] = h;
        }
        #pragma unroll
        for (int i = 0; i < BT; ++i) buf[i] = nbuf[i];
    }
    ((float2*)E)[g * P_DIM + p] = h;
}

// ---- k3: sequential scan over chunk states (1 block, 128 threads) ----
__global__ void k3(const float* __restrict__ E, const float* __restrict__ dApow,
                   float* __restrict__ Hin) {
    int p = threadIdx.x;
    float2 aS = ((const float2*)dApow)[(size_t)CHUNK * P_DIM + p];
    float2 h = make_float2(0.f, 0.f);
    const float2* e = (const float2*)E;
    float2* hin = (float2*)Hin;
    float2 buf[BT], nbuf[BT];
    #pragma unroll
    for (int i = 0; i < BT; ++i) buf[i] = e[i * P_DIM + p];
    const int NB = NCHUNK / BT;   // 32
    for (int b = 0; b < NB; ++b) {
        if (b + 1 < NB) {
            #pragma unroll
            for (int i = 0; i < BT; ++i) nbuf[i] = e[((b + 1) * BT + i) * P_DIM + p];
        }
        #pragma unroll
        for (int i = 0; i < BT; ++i) {
            hin[(b * BT + i) * P_DIM + p] = h;
            h = cfma(aS, h, buf[i]);
        }
        #pragma unroll
        for (int i = 0; i < BT; ++i) buf[i] = nbuf[i];
    }
}

// ---- k4: y[l][h] = 2*Re(sum_p (h_local+dA^{i+1}*Hin)*C[h][p]) + x*D ----
__global__ __launch_bounds__(256, 2) void k4(const float* __restrict__ x,
                                             const float* __restrict__ hbuf,
                                             const float* __restrict__ Ct,
                                             const float* __restrict__ dApow,
                                             const float* __restrict__ Hin,
                                             const float* __restrict__ Dv,
                                             float* __restrict__ y) {
    __shared__ float2 hs[32][33];     // 8.4 KB
    __shared__ float2 Cs[32][128];    // 32 KB
    int t = threadIdx.x;
    int l0 = blockIdx.x * 32;
    int g = l0 / CHUNK;
    int th = t & 31, tl = t >> 5;
    float acc[4][4];
    #pragma unroll
    for (int a = 0; a < 4; ++a)
        #pragma unroll
        for (int b = 0; b < 4; ++b) acc[a][b] = 0.f;

    int spp = t & 31;          // staging p within tile
    int slb = t >> 5;          // staging row base
    for (int pt = 0; pt < 4; ++pt) {
        int p0 = pt * 32;
        __syncthreads();
        // stage hs with fixup: 32l x 32p
        float2 hi = ((const float2*)Hin)[g * P_DIM + p0 + spp];
        #pragma unroll
        for (int j = 0; j < 4; ++j) {
            int l = j * 8 + slb;
            int gl = l0 + l;
            float2 hl = ((const float2*)hbuf)[(size_t)gl * P_DIM + p0 + spp];
            int k = (gl & (CHUNK - 1)) + 1;
            float2 ap = ((const float2*)dApow)[(size_t)k * P_DIM + p0 + spp];
            hs[l][spp] = cfma(ap, hi, hl);
        }
        // stage Cs: 32p x 128h complex = 2048 float4, 8 per thread (Ct is [p][h])
        #pragma unroll
        for (int j = 0; j < 8; ++j) {
            int f = j * 256 + t;
            int pp = f >> 6, h4 = f & 63;
            float4 v = *(const float4*)(Ct + ((size_t)(p0 + pp) * H_DIM + h4 * 2) * 2);
            *(float4*)(&Cs[pp][h4 * 2]) = v;
        }
        __syncthreads();
        #pragma unroll 8
        for (int pp = 0; pp < 32; ++pp) {
            float2 hv[4], cv[4];
            #pragma unroll
            for (int j = 0; j < 4; ++j) hv[j] = hs[tl * 4 + j][pp];
            #pragma unroll
            for (int j = 0; j < 4; ++j) cv[j] = Cs[pp][th + 32 * j];
            #pragma unroll
            for (int jl = 0; jl < 4; ++jl)
                #pragma unroll
                for (int jh = 0; jh < 4; ++jh) {
                    acc[jl][jh] = fmaf(hv[jl].x,  cv[jh].x, acc[jl][jh]);
                    acc[jl][jh] = fmaf(-hv[jl].y, cv[jh].y, acc[jl][jh]);
                }
        }
    }
    // epilogue: y = 2*acc + x*D
    #pragma unroll
    for (int jh = 0; jh < 4; ++jh) {
        int h = th + 32 * jh;
        float d = Dv[h];
        #pragma unroll
        for (int jl = 0; jl < 4; ++jl) {
            int l = l0 + tl * 4 + jl;
            float xv = x[(size_t)l * H_DIM + h];
            y[(size_t)l * H_DIM + h] = fmaf(xv, d, 2.f * acc[jl][jh]);
        }
    }
}

extern "C" void kernel_launch(void* const* d_in, const int* in_sizes, int n_in,
                              void* d_out, int out_size, void* d_ws, size_t ws_size,
                              hipStream_t stream) {
    const float* x     = (const float*)d_in[0];
    const float* Arl   = (const float*)d_in[1];
    const float* Ai    = (const float*)d_in[2];
    const float* Bre   = (const float*)d_in[3];
    const float* Bim   = (const float*)d_in[4];
    const float* Cre   = (const float*)d_in[5];
    const float* Cim   = (const float*)d_in[6];
    const float* Dv    = (const float*)d_in[7];
    const float* invdt = (const float*)d_in[8];
    float* y  = (float*)d_out;
    float* ws = (float*)d_ws;

    k0a<<<1, 128, 0, stream>>>(Arl, Ai, invdt, ws + OFF_DA, ws + OFF_SC, ws + OFF_POW);
    k0b<<<64, 256, 0, stream>>>(Bre, Bim, Cre, Cim, ws + OFF_SC, ws + OFF_DBT, ws + OFF_CT);
    k1<<<L_LEN / K1_ROWS, 256, 0, stream>>>(x, ws + OFF_DBT, ws + OFF_BU);
    k2<<<NCHUNK / 2, 256, 0, stream>>>(ws + OFF_BU, ws + OFF_DA, ws + OFF_E);
    k3<<<1, 128, 0, stream>>>(ws + OFF_E, ws + OFF_POW, ws + OFF_HIN);
    k4<<<L_LEN / 32, 256, 0, stream>>>(x, ws + OFF_BU, ws + OFF_CT, ws + OFF_POW,
                                       ws + OFF_HIN, Dv, y);
}

// Round 2
// 190.367 us; speedup vs baseline: 1.7676x; 1.7676x over previous
//
#include <hip/hip_runtime.h>

#define L_LEN 131072
#define H_DIM 128
#define P_DIM 128
#define CHUNK 256
#define NCHUNK (L_LEN / CHUNK)   // 512
#define BT 16

typedef unsigned int uint32;
typedef unsigned short u16;
typedef short bf16x8 __attribute__((ext_vector_type(8)));
typedef float f32x4 __attribute__((ext_vector_type(4)));

// ---- workspace layout (float offsets) ----
constexpr size_t OFF_BU  = 0;
constexpr size_t N_BU    = (size_t)L_LEN * P_DIM * 2;          // 33,554,432 floats
constexpr size_t OFF_DA  = OFF_BU + N_BU;
constexpr size_t OFF_SC  = OFF_DA + 2 * P_DIM;
constexpr size_t OFF_POW = OFF_SC + 2 * P_DIM;
constexpr size_t N_POW   = (size_t)(CHUNK + 1) * P_DIM * 2;    // 65,792
constexpr size_t OFF_E   = OFF_POW + N_POW;                    // 512*256
constexpr size_t OFF_HIN = OFF_E + (size_t)NCHUNK * P_DIM * 2;
constexpr size_t OFF_W1H = OFF_HIN + (size_t)NCHUNK * P_DIM * 2; // 256x128 u16 = 16384 fl
constexpr size_t OFF_W1L = OFF_W1H + 16384;
constexpr size_t OFF_W2H = OFF_W1L + 16384;                      // 128x256 u16
constexpr size_t OFF_W2L = OFF_W2H + 16384;
// total ≈ 135.8 MB

__device__ __forceinline__ u16 f2bf(float v) {
    uint32 u = __builtin_bit_cast(uint32, v);
    uint32 r = u + 0x7FFFu + ((u >> 16) & 1u);
    return (u16)(r >> 16);
}
__device__ __forceinline__ float bf2f(u16 h) {
    uint32 u = ((uint32)h) << 16;
    return __builtin_bit_cast(float, u);
}
__device__ __forceinline__ float2 cfma(float2 a, float2 h, float2 c) {
    float2 r;
    r.x = fmaf(a.x, h.x, fmaf(-a.y, h.y, c.x));
    r.y = fmaf(a.x, h.y, fmaf(a.y, h.x, c.y));
    return r;
}

// ---- k0a: per-mode scalars + dA power table ----
__global__ void k0a(const float* __restrict__ Arl, const float* __restrict__ Ai,
                    const float* __restrict__ invdt,
                    float* __restrict__ dA, float* __restrict__ sc,
                    float* __restrict__ dApow) {
    int p = threadIdx.x;
    if (p >= P_DIM) return;
    float idt = invdt[p];
    float dt = (idt > 20.f) ? idt : log1pf(expf(idt));   // softplus
    float ar = Arl[p], ai = Ai[p];
    float zr = 0.5f * dt * ar, zi = 0.5f * dt * ai;
    float dr = 1.f - zr, di = -zi;
    float inv = 1.f / (dr * dr + di * di);
    float blr = dr * inv, bli = -di * inv;
    float nr = 1.f + zr, ni = zi;
    float dar = fmaf(blr, nr, -bli * ni);
    float dai = fmaf(blr, ni,  bli * nr);
    dA[2 * p] = dar; dA[2 * p + 1] = dai;
    sc[2 * p] = blr * dt; sc[2 * p + 1] = bli * dt;
    float pr = 1.f, pi = 0.f;
    dApow[p * 2] = pr; dApow[p * 2 + 1] = pi;
    for (int k = 1; k <= CHUNK; ++k) {
        float npr = fmaf(pr, dar, -pi * dai);
        float npi = fmaf(pr, dai,  pi * dar);
        pr = npr; pi = npi;
        dApow[((size_t)k * P_DIM + p) * 2]     = pr;
        dApow[((size_t)k * P_DIM + p) * 2 + 1] = pi;
    }
}

// ---- k0b: W1T[q][h] = component of dB[p][h] (q=2p+c); W2T[h][q] = (Cr, -Ci) ----
__global__ void k0b(const float* __restrict__ Bre, const float* __restrict__ Bim,
                    const float* __restrict__ Cre, const float* __restrict__ Cim,
                    const float* __restrict__ sc,
                    u16* __restrict__ W1H, u16* __restrict__ W1L,
                    u16* __restrict__ W2H, u16* __restrict__ W2L) {
    int i = blockIdx.x * 256 + threadIdx.x;      // 0..16383
    int p = i >> 7, h = i & 127;
    float2 s = ((const float2*)sc)[p];
    float br = Bre[i], bi = Bim[i];
    float re = fmaf(s.x, br, -s.y * bi);
    float im = fmaf(s.x, bi,  s.y * br);
    u16 hr = f2bf(re); W1H[(2 * p) * H_DIM + h]     = hr; W1L[(2 * p) * H_DIM + h]     = f2bf(re - bf2f(hr));
    u16 hi = f2bf(im); W1H[(2 * p + 1) * H_DIM + h] = hi; W1L[(2 * p + 1) * H_DIM + h] = f2bf(im - bf2f(hi));
    // C is (H,P): element [h2][p2]
    int h2 = i >> 7, p2 = i & 127;
    float cr = Cre[i], ci = -Cim[i];
    u16 chr = f2bf(cr); W2H[h2 * 256 + 2 * p2]     = chr; W2L[h2 * 256 + 2 * p2]     = f2bf(cr - bf2f(chr));
    u16 chi = f2bf(ci); W2H[h2 * 256 + 2 * p2 + 1] = chi; W2L[h2 * 256 + 2 * p2 + 1] = f2bf(ci - bf2f(chi));
}

// ---- k1: Bu(131072x256) = X(131072x128) @ W1(128x256), split-bf16 MFMA ----
__global__ __launch_bounds__(256) void k1(const float* __restrict__ x,
                                          const u16* __restrict__ W1H,
                                          const u16* __restrict__ W1L,
                                          float* __restrict__ Bu) {
    __shared__ u16 As_hi[128][40], As_lo[128][40];   // [M][K-step], +8 pad
    __shared__ u16 Bs_hi[256][40], Bs_lo[256][40];   // [N][K-step], +8 pad
    int t = threadIdx.x;
    int lane = t & 63, wid = t >> 6;
    int wr = wid >> 1, wc = wid & 1;                 // wave grid 2x2: 64 rows x 128 cols
    size_t l0 = (size_t)blockIdx.x * 128;
    f32x4 acc[4][8];
    #pragma unroll
    for (int a = 0; a < 4; ++a)
        #pragma unroll
        for (int b = 0; b < 8; ++b) acc[a][b] = (f32x4)0.f;

    for (int kt = 0; kt < 4; ++kt) {
        __syncthreads();
        // stage A: 128 rows x 32 k fp32 -> split bf16
        #pragma unroll
        for (int j = 0; j < 4; ++j) {
            int f = j * 256 + t; int row = f >> 3, c4 = f & 7;
            float4 v = *(const float4*)(x + (l0 + row) * H_DIM + kt * 32 + c4 * 4);
            ushort4 h4, l4;
            h4.x = f2bf(v.x); l4.x = f2bf(v.x - bf2f(h4.x));
            h4.y = f2bf(v.y); l4.y = f2bf(v.y - bf2f(h4.y));
            h4.z = f2bf(v.z); l4.z = f2bf(v.z - bf2f(h4.z));
            h4.w = f2bf(v.w); l4.w = f2bf(v.w - bf2f(h4.w));
            *(ushort4*)&As_hi[row][c4 * 4] = h4;
            *(ushort4*)&As_lo[row][c4 * 4] = l4;
        }
        // stage B: W1T rows (contiguous k) -> LDS [N][32]
        #pragma unroll
        for (int j = 0; j < 4; ++j) {
            int f = j * 256 + t; int q = f >> 2, c = f & 3;
            *(float4*)&Bs_hi[q][c * 8] = *(const float4*)(W1H + (size_t)q * H_DIM + kt * 32 + c * 8);
            *(float4*)&Bs_lo[q][c * 8] = *(const float4*)(W1L + (size_t)q * H_DIM + kt * 32 + c * 8);
        }
        __syncthreads();
        int ar = lane & 15, ak = (lane >> 4) * 8;
        bf16x8 a_hi[4], a_lo[4];
        #pragma unroll
        for (int mf = 0; mf < 4; ++mf) {
            a_hi[mf] = *(const bf16x8*)&As_hi[wr * 64 + mf * 16 + ar][ak];
            a_lo[mf] = *(const bf16x8*)&As_lo[wr * 64 + mf * 16 + ar][ak];
        }
        #pragma unroll
        for (int nf = 0; nf < 8; ++nf) {
            bf16x8 b_hi = *(const bf16x8*)&Bs_hi[wc * 128 + nf * 16 + ar][ak];
            bf16x8 b_lo = *(const bf16x8*)&Bs_lo[wc * 128 + nf * 16 + ar][ak];
            #pragma unroll
            for (int mf = 0; mf < 4; ++mf) {
                acc[mf][nf] = __builtin_amdgcn_mfma_f32_16x16x32_bf16(a_hi[mf], b_hi, acc[mf][nf], 0, 0, 0);
                acc[mf][nf] = __builtin_amdgcn_mfma_f32_16x16x32_bf16(a_lo[mf], b_hi, acc[mf][nf], 0, 0, 0);
                acc[mf][nf] = __builtin_amdgcn_mfma_f32_16x16x32_bf16(a_hi[mf], b_lo, acc[mf][nf], 0, 0, 0);
            }
        }
    }
    int sr = (lane >> 4) * 4, scn = lane & 15;
    #pragma unroll
    for (int mf = 0; mf < 4; ++mf)
        #pragma unroll
        for (int nf = 0; nf < 8; ++nf)
            #pragma unroll
            for (int r = 0; r < 4; ++r) {
                int m = wr * 64 + mf * 16 + sr + r;
                int n = wc * 128 + nf * 16 + scn;
                Bu[(l0 + m) * 256 + n] = acc[mf][nf][r];
            }
}

// ---- k2: per-chunk local scans; overwrite Bu with h_local; emit end states ----
__global__ __launch_bounds__(256) void k2(float* __restrict__ Bu,
                                          const float* __restrict__ dA,
                                          float* __restrict__ E) {
    int t = threadIdx.x;
    int p = t & 127;
    int g = blockIdx.x * 2 + (t >> 7);
    float2 a = ((const float2*)dA)[p];
    float2* bu = (float2*)Bu + (size_t)g * CHUNK * P_DIM + p;
    float2 h = make_float2(0.f, 0.f);
    float2 buf[BT], nbuf[BT];
    #pragma unroll
    for (int i = 0; i < BT; ++i) buf[i] = bu[i * P_DIM];
    const int NB = CHUNK / BT;
    for (int b = 0; b < NB; ++b) {
        if (b + 1 < NB) {
            #pragma unroll
            for (int i = 0; i < BT; ++i) nbuf[i] = bu[((b + 1) * BT + i) * P_DIM];
        }
        #pragma unroll
        for (int i = 0; i < BT; ++i) {
            h = cfma(a, h, buf[i]);
            bu[(b * BT + i) * P_DIM] = h;
        }
        #pragma unroll
        for (int i = 0; i < BT; ++i) buf[i] = nbuf[i];
    }
    ((float2*)E)[g * P_DIM + p] = h;
}

// ---- k3: sequential scan over chunk states (1 block, 128 threads) ----
__global__ void k3(const float* __restrict__ E, const float* __restrict__ dApow,
                   float* __restrict__ Hin) {
    int p = threadIdx.x;
    float2 aS = ((const float2*)dApow)[(size_t)CHUNK * P_DIM + p];
    float2 h = make_float2(0.f, 0.f);
    const float2* e = (const float2*)E;
    float2* hin = (float2*)Hin;
    float2 buf[BT], nbuf[BT];
    #pragma unroll
    for (int i = 0; i < BT; ++i) buf[i] = e[i * P_DIM + p];
    const int NB = NCHUNK / BT;   // 32
    for (int b = 0; b < NB; ++b) {
        if (b + 1 < NB) {
            #pragma unroll
            for (int i = 0; i < BT; ++i) nbuf[i] = e[((b + 1) * BT + i) * P_DIM + p];
        }
        #pragma unroll
        for (int i = 0; i < BT; ++i) {
            hin[(b * BT + i) * P_DIM + p] = h;
            h = cfma(aS, h, buf[i]);
        }
        #pragma unroll
        for (int i = 0; i < BT; ++i) buf[i] = nbuf[i];
    }
}

// ---- k4: y = 2*Re((h_local + dA^k*Hin) @ C^T) + x*D, split-bf16 MFMA ----
__global__ __launch_bounds__(256) void k4(const float* __restrict__ x,
                                          const float* __restrict__ hbuf,
                                          const u16* __restrict__ W2H,
                                          const u16* __restrict__ W2L,
                                          const float* __restrict__ dApow,
                                          const float* __restrict__ Hin,
                                          const float* __restrict__ Dv,
                                          float* __restrict__ y) {
    __shared__ u16 As_hi[128][40], As_lo[128][40];
    __shared__ u16 Bs_hi[128][40], Bs_lo[128][40];
    int t = threadIdx.x, lane = t & 63, wid = t >> 6;
    int wr = wid >> 1, wc = wid & 1;                 // 64 rows x 64 cols per wave
    size_t l0 = (size_t)blockIdx.x * 128;
    int g = blockIdx.x >> 1;                         // chunk index (CHUNK=256, BM=128)
    int pc = t & 15;                                 // complex col in step
    int rg = t >> 4;                                 // 0..15 row group
    f32x4 acc[4][4];
    #pragma unroll
    for (int a = 0; a < 4; ++a)
        #pragma unroll
        for (int b = 0; b < 4; ++b) acc[a][b] = (f32x4)0.f;

    for (int kt = 0; kt < 8; ++kt) {
        __syncthreads();
        int pglob = kt * 16 + pc;
        float2 hg = ((const float2*)Hin)[(size_t)g * P_DIM + pglob];
        // stage A with fixup: 128 rows x 16 complex
        #pragma unroll
        for (int j = 0; j < 8; ++j) {
            int row = j * 16 + rg;
            size_t lg = l0 + row;
            float2 hl = ((const float2*)hbuf)[lg * P_DIM + pglob];
            int k = (int)(lg & (CHUNK - 1)) + 1;
            float2 ap = ((const float2*)dApow)[(size_t)k * P_DIM + pglob];
            float2 he = cfma(ap, hg, hl);
            u16 hre = f2bf(he.x), lre = f2bf(he.x - bf2f(hre));
            u16 him = f2bf(he.y), lim = f2bf(he.y - bf2f(him));
            ushort2 hv; hv.x = hre; hv.y = him;
            ushort2 lv; lv.x = lre; lv.y = lim;
            *(ushort2*)&As_hi[row][2 * pc] = hv;
            *(ushort2*)&As_lo[row][2 * pc] = lv;
        }
        // stage B: W2T rows -> LDS [N=128][32]
        #pragma unroll
        for (int j = 0; j < 2; ++j) {
            int f = j * 256 + t; int h = f >> 2, c = f & 3;
            *(float4*)&Bs_hi[h][c * 8] = *(const float4*)(W2H + (size_t)h * 256 + kt * 32 + c * 8);
            *(float4*)&Bs_lo[h][c * 8] = *(const float4*)(W2L + (size_t)h * 256 + kt * 32 + c * 8);
        }
        __syncthreads();
        int ar = lane & 15, ak = (lane >> 4) * 8;
        bf16x8 a_hi[4], a_lo[4];
        #pragma unroll
        for (int mf = 0; mf < 4; ++mf) {
            a_hi[mf] = *(const bf16x8*)&As_hi[wr * 64 + mf * 16 + ar][ak];
            a_lo[mf] = *(const bf16x8*)&As_lo[wr * 64 + mf * 16 + ar][ak];
        }
        #pragma unroll
        for (int nf = 0; nf < 4; ++nf) {
            bf16x8 b_hi = *(const bf16x8*)&Bs_hi[wc * 64 + nf * 16 + ar][ak];
            bf16x8 b_lo = *(const bf16x8*)&Bs_lo[wc * 64 + nf * 16 + ar][ak];
            #pragma unroll
            for (int mf = 0; mf < 4; ++mf) {
                acc[mf][nf] = __builtin_amdgcn_mfma_f32_16x16x32_bf16(a_hi[mf], b_hi, acc[mf][nf], 0, 0, 0);
                acc[mf][nf] = __builtin_amdgcn_mfma_f32_16x16x32_bf16(a_lo[mf], b_hi, acc[mf][nf], 0, 0, 0);
                acc[mf][nf] = __builtin_amdgcn_mfma_f32_16x16x32_bf16(a_hi[mf], b_lo, acc[mf][nf], 0, 0, 0);
            }
        }
    }
    // epilogue: y = 2*acc + x*D
    int sr = (lane >> 4) * 4, scn = lane & 15;
    #pragma unroll
    for (int nf = 0; nf < 4; ++nf) {
        int h = wc * 64 + nf * 16 + scn;
        float d = Dv[h];
        #pragma unroll
        for (int mf = 0; mf < 4; ++mf)
            #pragma unroll
            for (int r = 0; r < 4; ++r) {
                int m = wr * 64 + mf * 16 + sr + r;
                size_t lg = l0 + m;
                y[lg * H_DIM + h] = fmaf(x[lg * H_DIM + h], d, 2.f * acc[mf][nf][r]);
            }
    }
}

extern "C" void kernel_launch(void* const* d_in, const int* in_sizes, int n_in,
                              void* d_out, int out_size, void* d_ws, size_t ws_size,
                              hipStream_t stream) {
    const float* x     = (const float*)d_in[0];
    const float* Arl   = (const float*)d_in[1];
    const float* Ai    = (const float*)d_in[2];
    const float* Bre   = (const float*)d_in[3];
    const float* Bim   = (const float*)d_in[4];
    const float* Cre   = (const float*)d_in[5];
    const float* Cim   = (const float*)d_in[6];
    const float* Dv    = (const float*)d_in[7];
    const float* invdt = (const float*)d_in[8];
    float* y  = (float*)d_out;
    float* ws = (float*)d_ws;

    u16* w1h = (u16*)(ws + OFF_W1H);
    u16* w1l = (u16*)(ws + OFF_W1L);
    u16* w2h = (u16*)(ws + OFF_W2H);
    u16* w2l = (u16*)(ws + OFF_W2L);

    k0a<<<1, 128, 0, stream>>>(Arl, Ai, invdt, ws + OFF_DA, ws + OFF_SC, ws + OFF_POW);
    k0b<<<64, 256, 0, stream>>>(Bre, Bim, Cre, Cim, ws + OFF_SC, w1h, w1l, w2h, w2l);
    k1<<<L_LEN / 128, 256, 0, stream>>>(x, w1h, w1l, ws + OFF_BU);
    k2<<<NCHUNK / 2, 256, 0, stream>>>(ws + OFF_BU, ws + OFF_DA, ws + OFF_E);
    k3<<<1, 128, 0, stream>>>(ws + OFF_E, ws + OFF_POW, ws + OFF_HIN);
    k4<<<L_LEN / 128, 256, 0, stream>>>(x, ws + OFF_BU, w2h, w2l, ws + OFF_POW,
                                        ws + OFF_HIN, Dv, y);
}